// Round 18
// baseline (268.981 us; speedup 1.0000x reference)
//
#include <hip/hip_runtime.h>
#include <cmath>

#define NH   12
#define DH   64
#define AHD  768
#define BB   8
#define SLQ  1024
#define SLK  1024
#define DIM  768

typedef unsigned short u16;
typedef _Float16 f16x8 __attribute__((ext_vector_type(8)));
typedef __fp16   fp16x2 __attribute__((ext_vector_type(2)));
typedef float    f32x4 __attribute__((ext_vector_type(4)));

union F8 { f16x8 v; uint4 u4; u16 s[8]; };

__device__ inline u16 f2h(float f) {
  union { _Float16 h; u16 u; } c;
  c.h = (_Float16)f;
  return c.u;
}
__device__ inline f16x8 ldsF8(const u16* p) { F8 u; u.u4 = *(const uint4*)p; return u.v; }
__device__ inline unsigned pk2(float a, float b) {
  union { fp16x2 h; unsigned u; } c;
  c.h = __builtin_amdgcn_cvt_pkrtz(a, b);
  return c.u;
}
__device__ inline float fast_tanh(float x) {
  x = fminf(fmaxf(x, -10.f), 10.f);
  const float e = __expf(2.f * x);
  return (e - 1.f) * __builtin_amdgcn_rcpf(e + 1.f);
}
// async global->LDS, 16B/lane; lds dest = wave-uniform base + lane*16B (linear)
__device__ inline void g2lds16(const u16* g, u16* lds) {
  __builtin_amdgcn_global_load_lds((const __attribute__((address_space(1))) void*)g,
                                   (__attribute__((address_space(3))) void*)lds, 16, 0, 0);
}

// ---------------- one-shot f32 -> fp16 conversion (inputs + weights) ----------------
__global__ __launch_bounds__(256) void cvt_f16(
    const float* __restrict__ q, const float* __restrict__ k,
    const float* __restrict__ wq, const float* __restrict__ wk, const float* __restrict__ wv,
    u16* __restrict__ q16, u16* __restrict__ k16,
    u16* __restrict__ wq16, u16* __restrict__ wk16, u16* __restrict__ wv16) {
  const int y = blockIdx.y;
  const float* src; u16* dst; int n8;
  if (y == 0)      { src = q;  dst = q16;  n8 = (BB * SLQ * AHD) / 8; }
  else if (y == 1) { src = k;  dst = k16;  n8 = (BB * SLK * AHD) / 8; }
  else if (y == 2) { src = wq; dst = wq16; n8 = (AHD * DIM) / 8; }
  else if (y == 3) { src = wk; dst = wk16; n8 = (AHD * DIM) / 8; }
  else             { src = wv; dst = wv16; n8 = (AHD * DIM) / 8; }
  for (int i = blockIdx.x * 256 + threadIdx.x; i < n8; i += 512 * 256) {
    f32x4 a = __builtin_nontemporal_load((const f32x4*)src + i * 2);
    f32x4 b = __builtin_nontemporal_load((const f32x4*)src + i * 2 + 1);
    F8 c;
    c.v = (f16x8){(_Float16)a[0], (_Float16)a[1], (_Float16)a[2], (_Float16)a[3],
                  (_Float16)b[0], (_Float16)b[1], (_Float16)b[2], (_Float16)b[3]};
    ((uint4*)dst)[i] = c.u4;
  }
}

// ---------------- fused fp16-MFMA projections: z=0 Q, z=1 K, z=2 V(transposed out) ----------------
// Double-buffered LDS; staging via global_load_lds (linear dest, inverse-swizzled src).
__global__ __launch_bounds__(256) void proj_mfma(
    const u16* __restrict__ X16q, const u16* __restrict__ X16k,
    const u16* __restrict__ Wq16, const u16* __restrict__ Wk16, const u16* __restrict__ Wv16,
    const float* __restrict__ bq, const float* __restrict__ bk, const float* __restrict__ bv,
    u16* __restrict__ Qb, u16* __restrict__ Kb, u16* __restrict__ Vtb) {
  __shared__ __align__(16) u16 As[2][128 * 32];
  __shared__ __align__(16) u16 Bs[2][128 * 32];
  const int t  = threadIdx.x;
  const int w  = t >> 6, l = t & 63;
  const int lr = l & 15, lg = l >> 4;
  const int wr = w >> 1, wc = w & 1;
  const int bm = blockIdx.x * 128, bn = blockIdx.y * 128;
  const int z  = blockIdx.z;

  const u16*   Xs = (z == 0) ? X16q : X16k;
  const u16*   Ws = (z == 0) ? Wq16 : (z == 1 ? Wk16 : Wv16);
  const float* bs = (z == 0) ? bq   : (z == 1 ? bk   : bv);
  u16* Y  = (z == 0) ? Qb : (z == 1 ? Kb : nullptr);
  u16* Yt = (z == 2) ? Vtb : nullptr;

  // per-lane source mapping for linear-dest staging:
  // LDS u16 off = (2w+c)*512 + lane*8 -> srow=(2w+c)*16+l/4, chunk=(l&3)^(srow&3)
  int srowc[2], joffc[2];
#pragma unroll
  for (int cc = 0; cc < 2; ++cc) {
    srowc[cc] = (w * 2 + cc) * 16 + (l >> 2);
    joffc[cc] = ((l & 3) ^ (srowc[cc] & 3)) * 8;
  }

  f32x4 acc[4][4];
#pragma unroll
  for (int i = 0; i < 4; ++i)
#pragma unroll
    for (int j = 0; j < 4; ++j) acc[i][j] = (f32x4){0.f, 0.f, 0.f, 0.f};

  // prologue: stage k0 = 0 into buffer 0
#pragma unroll
  for (int cc = 0; cc < 2; ++cc) {
    g2lds16(Xs + (size_t)(bm + srowc[cc]) * DIM + joffc[cc], &As[0][(w * 2 + cc) * 512]);
    g2lds16(Ws + (size_t)(bn + srowc[cc]) * DIM + joffc[cc], &Bs[0][(w * 2 + cc) * 512]);
  }
  __syncthreads();

  const int NK = DIM / 32;  // 24
  for (int ks = 0; ks < NK; ++ks) {
    const int cur = ks & 1;
    if (ks < NK - 1) {
      const int k0 = (ks + 1) * 32;
#pragma unroll
      for (int cc = 0; cc < 2; ++cc) {
        g2lds16(Xs + (size_t)(bm + srowc[cc]) * DIM + k0 + joffc[cc], &As[cur ^ 1][(w * 2 + cc) * 512]);
        g2lds16(Ws + (size_t)(bn + srowc[cc]) * DIM + k0 + joffc[cc], &Bs[cur ^ 1][(w * 2 + cc) * 512]);
      }
    }

    f16x8 af[4], bf[4];
#pragma unroll
    for (int mt = 0; mt < 4; ++mt) {
      const int row = wr * 64 + mt * 16 + lr;
      af[mt] = ldsF8(&As[cur][row * 32 + (lg ^ (row & 3)) * 8]);
    }
#pragma unroll
    for (int nt = 0; nt < 4; ++nt) {
      const int row = wc * 64 + nt * 16 + lr;
      bf[nt] = ldsF8(&Bs[cur][row * 32 + (lg ^ (row & 3)) * 8]);
    }
    __builtin_amdgcn_s_setprio(1);
#pragma unroll
    for (int mt = 0; mt < 4; ++mt)
#pragma unroll
      for (int nt = 0; nt < 4; ++nt)
        acc[mt][nt] = __builtin_amdgcn_mfma_f32_16x16x32_f16(af[mt], bf[nt], acc[mt][nt], 0, 0, 0);
    __builtin_amdgcn_s_setprio(0);
    __syncthreads();
  }

  float bvn[4];
#pragma unroll
  for (int nt = 0; nt < 4; ++nt) bvn[nt] = bs[bn + wc * 64 + nt * 16 + lr];

#pragma unroll
  for (int mt = 0; mt < 4; ++mt) {
    const int m0 = bm + wr * 64 + mt * 16 + lg * 4;
#pragma unroll
    for (int nt = 0; nt < 4; ++nt) {
      const int n = bn + wc * 64 + nt * 16 + lr;
#pragma unroll
      for (int r = 0; r < 4; ++r) {
        const float val = acc[mt][nt][r] + bvn[nt];
        const u16 hv = f2h(val);
        const int m = m0 + r;
        if (Y)  Y[(size_t)m * DIM + n] = hv;
        if (Yt) {
          const int b2 = m >> 10, ll = m & 1023;
          Yt[((size_t)b2 * DIM + n) * SLK + ll] = hv;
        }
      }
    }
  }
}

// ---------------- swapped-QK^T MFMA attention pass ----------------
// Staging via global_load_lds (linear dest + inverse-swizzled per-lane source);
// P redistribution fully in-register (cvt_pk + permlane32/16_swap).
template <bool DO_PV, bool NORM_P, bool ACC_L>
__device__ __forceinline__ void attn_pass(
    const u16* __restrict__ Kg, const u16* __restrict__ Vg,
    const float* __restrict__ Msf,
    u16* __restrict__ Ks0, u16* __restrict__ Ks1,
    u16* __restrict__ Vs0, u16* __restrict__ Vs1,
    const f16x8 (&qa)[2][2], const int lr, const int lg,
    float (&lrun)[2], const float (&invl)[2], f32x4 (&oacc)[2][4],
    float* __restrict__ Pout, const size_t poutRow0,
    const int w, const int l) {
  const float scale = 0.03608439182435161f;  // 1/sqrt(768)
  const int NT = SLK / 64;                   // 16

  // per-lane source mapping: LDS off = (2w+c)*512 + lane*8 u16
  // -> row=(2w+c)*8 + l/8, chunk=(l&7)^(row&7)
  int rowc[2], joffc[2];
#pragma unroll
  for (int cc = 0; cc < 2; ++cc) {
    rowc[cc]  = (w * 2 + cc) * 8 + (l >> 3);
    joffc[cc] = ((l & 7) ^ (rowc[cc] & 7)) * 8;
  }

  // prologue: stage tile 0
#pragma unroll
  for (int cc = 0; cc < 2; ++cc) {
    g2lds16(Kg + (size_t)rowc[cc] * AHD + joffc[cc], Ks0 + (w * 2 + cc) * 512);
    if (DO_PV)
      g2lds16(Vg + (size_t)rowc[cc] * SLK + joffc[cc], Vs0 + (w * 2 + cc) * 512);
  }
  __syncthreads();

#pragma unroll 2
  for (int kt = 0; kt < NT; ++kt) {
    const int k0 = kt * 64;
    u16* Kc = (kt & 1) ? Ks1 : Ks0;
    u16* Kn = (kt & 1) ? Ks0 : Ks1;
    u16* Vc = (kt & 1) ? Vs1 : Vs0;
    u16* Vn = (kt & 1) ? Vs0 : Vs1;

    // stage tile kt+1 (DMA overlaps this tile's compute; barrier drains)
    if (kt + 1 < NT) {
#pragma unroll
      for (int cc = 0; cc < 2; ++cc) {
        g2lds16(Kg + (size_t)(k0 + 64 + rowc[cc]) * AHD + joffc[cc], Kn + (w * 2 + cc) * 512);
        if (DO_PV)
          g2lds16(Vg + (size_t)rowc[cc] * SLK + (k0 + 64) + joffc[cc], Vn + (w * 2 + cc) * 512);
      }
    }

    // QK^T (swapped): 16 MFMA
    f32x4 sacc[2][4];
#pragma unroll
    for (int mt = 0; mt < 2; ++mt)
#pragma unroll
      for (int ct = 0; ct < 4; ++ct) sacc[mt][ct] = (f32x4){0.f, 0.f, 0.f, 0.f};
    __builtin_amdgcn_s_setprio(1);
#pragma unroll
    for (int ct = 0; ct < 4; ++ct) {
      const int krow = ct * 16 + lr;
      f16x8 kf0 = ldsF8(&Kc[krow * 64 + ((lg)     ^ (krow & 7)) * 8]);
      f16x8 kf1 = ldsF8(&Kc[krow * 64 + ((4 + lg) ^ (krow & 7)) * 8]);
      sacc[0][ct] = __builtin_amdgcn_mfma_f32_16x16x32_f16(kf0, qa[0][0], sacc[0][ct], 0, 0, 0);
      sacc[0][ct] = __builtin_amdgcn_mfma_f32_16x16x32_f16(kf1, qa[0][1], sacc[0][ct], 0, 0, 0);
      sacc[1][ct] = __builtin_amdgcn_mfma_f32_16x16x32_f16(kf0, qa[1][0], sacc[1][ct], 0, 0, 0);
      sacc[1][ct] = __builtin_amdgcn_mfma_f32_16x16x32_f16(kf1, qa[1][1], sacc[1][ct], 0, 0, 0);
    }
    __builtin_amdgcn_s_setprio(0);

    // softmax numerators (p overwrites sacc); mask multiplicative from LDS
    float ps[2] = {0.f, 0.f};
#pragma unroll
    for (int ct = 0; ct < 4; ++ct) {
      const float4 mm = *(const float4*)&Msf[k0 + ct * 16 + lg * 4];
      const float m4[4] = {mm.x, mm.y, mm.z, mm.w};
#pragma unroll
      for (int mt = 0; mt < 2; ++mt)
#pragma unroll
        for (int r = 0; r < 4; ++r) {
          float p = __expf(sacc[mt][ct][r] * scale) * m4[r];
          if (NORM_P) p *= invl[mt];
          sacc[mt][ct][r] = p;
          if (ACC_L) ps[mt] += p;
        }
    }
    if (ACC_L) {
#pragma unroll
      for (int mt = 0; mt < 2; ++mt) {
        float s = ps[mt];
        s += __shfl_xor(s, 16);
        s += __shfl_xor(s, 32);
        lrun[mt] += s;
      }
    }

    if (NORM_P) {
      // p2 write: contiguous float4 along k per (mt,ct)
#pragma unroll
      for (int mt = 0; mt < 2; ++mt)
#pragma unroll
        for (int ct = 0; ct < 4; ++ct) {
          float4 pv = make_float4(sacc[mt][ct][0], sacc[mt][ct][1], sacc[mt][ct][2], sacc[mt][ct][3]);
          *(float4*)&Pout[(poutRow0 + mt * 16 + lr) * (size_t)SLK + k0 + ct * 16 + lg * 4] = pv;
        }
    }

    if (DO_PV) {
      // In-register P -> A-frag redistribution (T12)
      f16x8 pa[2][2];
#pragma unroll
      for (int mt = 0; mt < 2; ++mt) {
#pragma unroll
        for (int ks = 0; ks < 2; ++ks) {
          unsigned s00 = pk2(sacc[mt][2 * ks][0],     sacc[mt][2 * ks][1]);
          unsigned s01 = pk2(sacc[mt][2 * ks][2],     sacc[mt][2 * ks][3]);
          unsigned s10 = pk2(sacc[mt][2 * ks + 1][0], sacc[mt][2 * ks + 1][1]);
          unsigned s11 = pk2(sacc[mt][2 * ks + 1][2], sacc[mt][2 * ks + 1][3]);
          asm volatile("v_permlane32_swap_b32 %0, %1" : "+v"(s00), "+v"(s10));
          asm volatile("v_permlane16_swap_b32 %0, %1" : "+v"(s00), "+v"(s10));
          asm volatile("v_permlane32_swap_b32 %0, %1" : "+v"(s01), "+v"(s11));
          asm volatile("v_permlane16_swap_b32 %0, %1" : "+v"(s01), "+v"(s11));
          F8 u;
          u.u4 = make_uint4(s00, s01, s10, s11);
          pa[mt][ks] = u.v;
        }
      }

      // V fragments from LDS
      f16x8 vf[4][2];
#pragma unroll
      for (int dt = 0; dt < 4; ++dt) {
        const int vrow = dt * 16 + lr;
        vf[dt][0] = ldsF8(&Vc[vrow * 64 + ((lg)     ^ (vrow & 7)) * 8]);
        vf[dt][1] = ldsF8(&Vc[vrow * 64 + ((4 + lg) ^ (vrow & 7)) * 8]);
      }

      __builtin_amdgcn_s_setprio(1);
#pragma unroll
      for (int dt = 0; dt < 4; ++dt) {
        oacc[0][dt] = __builtin_amdgcn_mfma_f32_16x16x32_f16(pa[0][0], vf[dt][0], oacc[0][dt], 0, 0, 0);
        oacc[0][dt] = __builtin_amdgcn_mfma_f32_16x16x32_f16(pa[0][1], vf[dt][1], oacc[0][dt], 0, 0, 0);
        oacc[1][dt] = __builtin_amdgcn_mfma_f32_16x16x32_f16(pa[1][0], vf[dt][0], oacc[1][dt], 0, 0, 0);
        oacc[1][dt] = __builtin_amdgcn_mfma_f32_16x16x32_f16(pa[1][1], vf[dt][1], oacc[1][dt], 0, 0, 0);
      }
      __builtin_amdgcn_s_setprio(0);
    }

    __syncthreads();  // drains gload_lds -> next tile ready
  }
}

// MODE 0: stage 1 — single pass, unnormalized PV + denom, writes O fp16 + O^T fp16.
// MODE 1: stage 2 — pass1 (denoms), pass2 (normalized p2 f32 + PV), writes tanh f32.
template <int MODE>
__global__ __launch_bounds__(256) void attn_mfma(
    const u16* __restrict__ Qm, const u16* __restrict__ Km,
    const u16* __restrict__ Vt, const int* __restrict__ mask,
    u16* __restrict__ O16, u16* __restrict__ O16t,
    float* __restrict__ Of32, float* __restrict__ Pout) {
  __shared__ __align__(16) u16 Ks[2][64 * 64];
  __shared__ __align__(16) u16 Vs[2][64 * 64];
  __shared__ __align__(16) float Msf[SLK];

  const int t  = threadIdx.x;
  const int w  = t >> 6, l = t & 63;
  const int lr = l & 15, lg = l >> 4;
  const int b  = blockIdx.y, h = blockIdx.z;
  const int qr0 = blockIdx.x * 128 + w * 32;

  // mask -> LDS as float 0/1 (visible after attn_pass's prologue barrier)
  {
    const int4 mi = ((const int4*)(mask + (size_t)b * SLK))[t];
    *(float4*)&Msf[t * 4] = make_float4(mi.x == 1 ? 1.f : 0.f, mi.y == 1 ? 1.f : 0.f,
                                        mi.z == 1 ? 1.f : 0.f, mi.w == 1 ? 1.f : 0.f);
  }

  // Q fragments (held across passes)
  f16x8 qa[2][2];
#pragma unroll
  for (int mt = 0; mt < 2; ++mt) {
    const u16* qp = Qm + (size_t)(b * SLQ + qr0 + mt * 16 + lr) * AHD + h * DH + lg * 8;
    qa[mt][0] = *(const f16x8*)qp;
    qa[mt][1] = *(const f16x8*)(qp + 32);
  }

  const u16* Kg = Km + (size_t)b * SLK * AHD + h * DH;
  const u16* Vg = Vt + ((size_t)b * AHD + h * DH) * SLK;
  const size_t poutRow0 = ((size_t)(h * BB + b)) * SLQ + qr0;

  float lrun[2] = {0.f, 0.f};
  float invl[2] = {1.f, 1.f};
  f32x4 oacc[2][4];
#pragma unroll
  for (int mt = 0; mt < 2; ++mt)
#pragma unroll
    for (int dt = 0; dt < 4; ++dt) oacc[mt][dt] = (f32x4){0.f, 0.f, 0.f, 0.f};

  if (MODE == 0) {
    attn_pass<true, false, true>(Kg, Vg, Msf, Ks[0], Ks[1], Vs[0], Vs[1],
                                 qa, lr, lg, lrun, invl, oacc, nullptr, 0, w, l);
#pragma unroll
    for (int mt = 0; mt < 2; ++mt) invl[mt] = 1.f / lrun[mt];
#pragma unroll
    for (int mt = 0; mt < 2; ++mt) {
      float iv[4];
#pragma unroll
      for (int r = 0; r < 4; ++r) iv[r] = __shfl(invl[mt], lg * 4 + r);
#pragma unroll
      for (int dt = 0; dt < 4; ++dt) {
        const int d = h * DH + dt * 16 + lr;
#pragma unroll
        for (int r = 0; r < 4; ++r) {
          const int q = qr0 + mt * 16 + lg * 4 + r;
          const u16 hv = f2h(oacc[mt][dt][r] * iv[r]);
          O16[(size_t)(b * SLQ + q) * AHD + d] = hv;
          O16t[((size_t)b * AHD + d) * SLQ + q] = hv;
        }
      }
    }
  } else {
    attn_pass<false, false, true>(Kg, Vg, Msf, Ks[0], Ks[1], Vs[0], Vs[1],
                                  qa, lr, lg, lrun, invl, oacc, nullptr, 0, w, l);
#pragma unroll
    for (int mt = 0; mt < 2; ++mt) invl[mt] = 1.f / lrun[mt];
    attn_pass<true, true, false>(Kg, Vg, Msf, Ks[0], Ks[1], Vs[0], Vs[1],
                                 qa, lr, lg, lrun, invl, oacc, Pout, poutRow0, w, l);
#pragma unroll
    for (int mt = 0; mt < 2; ++mt)
#pragma unroll
      for (int dt = 0; dt < 4; ++dt) {
        const int d = h * DH + dt * 16 + lr;
#pragma unroll
        for (int r = 0; r < 4; ++r) {
          const int q = qr0 + mt * 16 + lg * 4 + r;
          Of32[(size_t)(b * SLQ + q) * AHD + d] = fast_tanh(oacc[mt][dt][r]);
        }
      }
  }
}

extern "C" void kernel_launch(void* const* d_in, const int* in_sizes, int n_in,
                              void* d_out, int out_size, void* d_ws, size_t ws_size,
                              hipStream_t stream) {
  const float* query = (const float*)d_in[0];
  const float* key   = (const float*)d_in[1];
  const int*   qmask = (const int*)d_in[2];
  const int*   kmask = (const int*)d_in[3];
  const float* Wq = (const float*)d_in[4];
  const float* bq = (const float*)d_in[5];
  const float* Wk = (const float*)d_in[6];
  const float* bk = (const float*)d_in[7];
  const float* Wv = (const float*)d_in[8];
  const float* bv = (const float*)d_in[9];

  float* out = (float*)d_out;
  const size_t bufE = (size_t)BB * SLQ * AHD;  // 6,291,456
  const size_t wE   = (size_t)AHD * DIM;       // 589,824
  float* p2out = out + bufE;                   // [H,B,LQ,LK] region (402 MB)

  // fp16 scratch in the not-yet-written p2 region (all dead before stage-2 writes p2):
  u16* Qb   = (u16*)p2out;
  u16* Kb   = Qb + bufE;
  u16* Vtb  = Kb + bufE;       // V^T [B,768,1024]
  u16* q16  = Vtb + bufE;
  u16* k16  = q16 + bufE;
  u16* wq16 = k16 + bufE;
  u16* wk16 = wq16 + wE;
  u16* wv16 = wk16 + wE;
  // O1 / O1^T in d_ws (read by stage 2 while p2 is written):
  u16* O1  = (u16*)d_ws;
  u16* O1t = O1 + bufE;

  cvt_f16<<<dim3(512, 5), dim3(256), 0, stream>>>(query, key, Wq, Wk, Wv,
                                                  q16, k16, wq16, wk16, wv16);

  dim3 pgrid(8192 / 128, DIM / 128, 3);  // (64, 6, 3) = 1152 blocks
  proj_mfma<<<pgrid, dim3(256), 0, stream>>>(q16, k16, wq16, wk16, wv16,
                                             bq, bk, bv, Qb, Kb, Vtb);

  dim3 agrid(SLQ / 128, BB, NH);  // (8, 8, 12) = 768 blocks, 3/CU
  attn_mfma<0><<<agrid, dim3(256), 0, stream>>>(Qb, Kb, Vtb, kmask, O1, O1t, nullptr, nullptr);
  attn_mfma<1><<<agrid, dim3(256), 0, stream>>>(O1, O1, O1t, qmask, nullptr, nullptr, out, p2out);
}

// Round 19
// 255.429 us; speedup vs baseline: 1.0531x; 1.0531x over previous
//
#include <hip/hip_runtime.h>
#include <cmath>

#define NH   12
#define DH   64
#define AHD  768
#define BB   8
#define SLQ  1024
#define SLK  1024
#define DIM  768

typedef unsigned short u16;
typedef _Float16 f16x8 __attribute__((ext_vector_type(8)));
typedef __fp16   fp16x2 __attribute__((ext_vector_type(2)));
typedef float    f32x4 __attribute__((ext_vector_type(4)));

union F8 { f16x8 v; uint4 u4; u16 s[8]; };

__device__ inline u16 f2h(float f) {
  union { _Float16 h; u16 u; } c;
  c.h = (_Float16)f;
  return c.u;
}
__device__ inline f16x8 ldsF8(const u16* p) { F8 u; u.u4 = *(const uint4*)p; return u.v; }
__device__ inline unsigned pk2(float a, float b) {
  union { fp16x2 h; unsigned u; } c;
  c.h = __builtin_amdgcn_cvt_pkrtz(a, b);
  return c.u;
}
__device__ inline float fast_tanh(float x) {
  x = fminf(fmaxf(x, -10.f), 10.f);           // e^20 can't overflow
  const float e = __expf(2.f * x);
  return (e - 1.f) * __builtin_amdgcn_rcpf(e + 1.f);
}

// ---------------- one-shot f32 -> fp16 conversion (inputs + weights) ----------------
__global__ __launch_bounds__(256) void cvt_f16(
    const float* __restrict__ q, const float* __restrict__ k,
    const float* __restrict__ wq, const float* __restrict__ wk, const float* __restrict__ wv,
    u16* __restrict__ q16, u16* __restrict__ k16,
    u16* __restrict__ wq16, u16* __restrict__ wk16, u16* __restrict__ wv16) {
  const int y = blockIdx.y;
  const float* src; u16* dst; int n8;
  if (y == 0)      { src = q;  dst = q16;  n8 = (BB * SLQ * AHD) / 8; }
  else if (y == 1) { src = k;  dst = k16;  n8 = (BB * SLK * AHD) / 8; }
  else if (y == 2) { src = wq; dst = wq16; n8 = (AHD * DIM) / 8; }
  else if (y == 3) { src = wk; dst = wk16; n8 = (AHD * DIM) / 8; }
  else             { src = wv; dst = wv16; n8 = (AHD * DIM) / 8; }
  for (int i = blockIdx.x * 256 + threadIdx.x; i < n8; i += 512 * 256) {
    f32x4 a = __builtin_nontemporal_load((const f32x4*)src + i * 2);
    f32x4 b = __builtin_nontemporal_load((const f32x4*)src + i * 2 + 1);
    F8 c;
    c.v = (f16x8){(_Float16)a[0], (_Float16)a[1], (_Float16)a[2], (_Float16)a[3],
                  (_Float16)b[0], (_Float16)b[1], (_Float16)b[2], (_Float16)b[3]};
    ((uint4*)dst)[i] = c.u4;
  }
}

// ---------------- fused fp16-MFMA projections: z=0 Q, z=1 K, z=2 V(transposed out) ----------------
// Double-buffered LDS, one barrier per K-step (T14: issue-early, write-late).
__global__ __launch_bounds__(256) void proj_mfma(
    const u16* __restrict__ X16q, const u16* __restrict__ X16k,
    const u16* __restrict__ Wq16, const u16* __restrict__ Wk16, const u16* __restrict__ Wv16,
    const float* __restrict__ bq, const float* __restrict__ bk, const float* __restrict__ bv,
    u16* __restrict__ Qb, u16* __restrict__ Kb, u16* __restrict__ Vtb) {
  __shared__ __align__(16) u16 As[2][128 * 32];
  __shared__ __align__(16) u16 Bs[2][128 * 32];
  const int t  = threadIdx.x;
  const int w  = t >> 6, l = t & 63;
  const int lr = l & 15, lg = l >> 4;
  const int wr = w >> 1, wc = w & 1;
  const int bm = blockIdx.x * 128, bn = blockIdx.y * 128;
  const int z  = blockIdx.z;

  const u16*   Xs = (z == 0) ? X16q : X16k;
  const u16*   Ws = (z == 0) ? Wq16 : (z == 1 ? Wk16 : Wv16);
  const float* bs = (z == 0) ? bq   : (z == 1 ? bk   : bv);
  u16* Y  = (z == 0) ? Qb : (z == 1 ? Kb : nullptr);
  u16* Yt = (z == 2) ? Vtb : nullptr;

  const int srow = t >> 1;
  const int half = t & 1;
  const int j0 = ((half * 2)     ^ (srow & 3)) * 8;
  const int j1 = ((half * 2 + 1) ^ (srow & 3)) * 8;

  f32x4 acc[4][4];
#pragma unroll
  for (int i = 0; i < 4; ++i)
#pragma unroll
    for (int j = 0; j < 4; ++j) acc[i][j] = (f32x4){0.f, 0.f, 0.f, 0.f};

  // prologue: stage k0 = 0 into buffer 0
  {
    const u16* sa = Xs + (size_t)(bm + srow) * DIM + half * 16;
    const u16* sb = Ws + (size_t)(bn + srow) * DIM + half * 16;
    *(uint4*)&As[0][srow * 32 + j0] = ((const uint4*)sa)[0];
    *(uint4*)&As[0][srow * 32 + j1] = ((const uint4*)sa)[1];
    *(uint4*)&Bs[0][srow * 32 + j0] = ((const uint4*)sb)[0];
    *(uint4*)&Bs[0][srow * 32 + j1] = ((const uint4*)sb)[1];
  }
  __syncthreads();

  const int NK = DIM / 32;  // 24
  for (int ks = 0; ks < NK; ++ks) {
    const int cur = ks & 1;
    const bool more = (ks < NK - 1);

    uint4 a0 = {}, a1 = {}, b0 = {}, b1 = {};
    if (more) {
      const int k0 = (ks + 1) * 32;
      const u16* sa = Xs + (size_t)(bm + srow) * DIM + k0 + half * 16;
      const u16* sb = Ws + (size_t)(bn + srow) * DIM + k0 + half * 16;
      a0 = ((const uint4*)sa)[0]; a1 = ((const uint4*)sa)[1];
      b0 = ((const uint4*)sb)[0]; b1 = ((const uint4*)sb)[1];
    }

    f16x8 af[4], bf[4];
#pragma unroll
    for (int mt = 0; mt < 4; ++mt) {
      const int row = wr * 64 + mt * 16 + lr;
      af[mt] = ldsF8(&As[cur][row * 32 + (lg ^ (row & 3)) * 8]);
    }
#pragma unroll
    for (int nt = 0; nt < 4; ++nt) {
      const int row = wc * 64 + nt * 16 + lr;
      bf[nt] = ldsF8(&Bs[cur][row * 32 + (lg ^ (row & 3)) * 8]);
    }
    __builtin_amdgcn_s_setprio(1);
#pragma unroll
    for (int mt = 0; mt < 4; ++mt)
#pragma unroll
      for (int nt = 0; nt < 4; ++nt)
        acc[mt][nt] = __builtin_amdgcn_mfma_f32_16x16x32_f16(af[mt], bf[nt], acc[mt][nt], 0, 0, 0);
    __builtin_amdgcn_s_setprio(0);

    if (more) {
      *(uint4*)&As[cur ^ 1][srow * 32 + j0] = a0;
      *(uint4*)&As[cur ^ 1][srow * 32 + j1] = a1;
      *(uint4*)&Bs[cur ^ 1][srow * 32 + j0] = b0;
      *(uint4*)&Bs[cur ^ 1][srow * 32 + j1] = b1;
    }
    __syncthreads();
  }

  float bvn[4];
#pragma unroll
  for (int nt = 0; nt < 4; ++nt) bvn[nt] = bs[bn + wc * 64 + nt * 16 + lr];

#pragma unroll
  for (int mt = 0; mt < 4; ++mt) {
    const int m0 = bm + wr * 64 + mt * 16 + lg * 4;
#pragma unroll
    for (int nt = 0; nt < 4; ++nt) {
      const int n = bn + wc * 64 + nt * 16 + lr;
#pragma unroll
      for (int r = 0; r < 4; ++r) {
        const float val = acc[mt][nt][r] + bvn[nt];
        const u16 hv = f2h(val);
        const int m = m0 + r;
        if (Y)  Y[(size_t)m * DIM + n] = hv;
        if (Yt) {
          const int b2 = m >> 10, ll = m & 1023;
          Yt[((size_t)b2 * DIM + n) * SLK + ll] = hv;
        }
      }
    }
  }
}

// ---------------- swapped-QK^T MFMA attention pass ----------------
// 2-deep prefetch; P redistribution fully in-register (cvt_pk + permlane32/16_swap).
template <bool DO_PV, bool NORM_P, bool ACC_L>
__device__ __forceinline__ void attn_pass(
    const u16* __restrict__ Kg, const u16* __restrict__ Vg,
    const float* __restrict__ Msf,
    u16* __restrict__ Ks0, u16* __restrict__ Ks1,
    u16* __restrict__ Vs0, u16* __restrict__ Vs1,
    const f16x8 (&qa)[2][2], const int lr, const int lg,
    float (&lrun)[2], const float (&invl)[2], f32x4 (&oacc)[2][4],
    float* __restrict__ Pout, const size_t poutRow0,
    const int skey, const int sj) {
  const float scale = 0.03608439182435161f;  // 1/sqrt(768)
  const int NT = SLK / 64;                   // 16

  // prologue: tile 0 -> LDS0 direct; issue tile 1 loads into regs
  {
    const u16* s = Kg + (size_t)skey * AHD + sj * 8;
    uint4 a = ((const uint4*)s)[0], b2 = ((const uint4*)s)[1];
    *(uint4*)&Ks0[skey * 64 + ((sj)     ^ (skey & 7)) * 8] = a;
    *(uint4*)&Ks0[skey * 64 + ((sj + 1) ^ (skey & 7)) * 8] = b2;
    if (DO_PV) {
      const u16* sv = Vg + (size_t)skey * SLK + sj * 8;
      uint4 va = ((const uint4*)sv)[0], vb = ((const uint4*)sv)[1];
      *(uint4*)&Vs0[skey * 64 + ((sj)     ^ (skey & 7)) * 8] = va;
      *(uint4*)&Vs0[skey * 64 + ((sj + 1) ^ (skey & 7)) * 8] = vb;
    }
  }
  uint4 kA0 = {}, kA1 = {}, vA0 = {}, vA1 = {};
  {
    const u16* s = Kg + (size_t)(64 + skey) * AHD + sj * 8;
    kA0 = ((const uint4*)s)[0]; kA1 = ((const uint4*)s)[1];
    if (DO_PV) {
      const u16* sv = Vg + (size_t)skey * SLK + 64 + sj * 8;
      vA0 = ((const uint4*)sv)[0]; vA1 = ((const uint4*)sv)[1];
    }
  }
  __syncthreads();

#pragma unroll 2
  for (int kt = 0; kt < NT; ++kt) {
    const int k0 = kt * 64;
    u16* Kc = (kt & 1) ? Ks1 : Ks0;
    u16* Kn = (kt & 1) ? Ks0 : Ks1;
    u16* Vc = (kt & 1) ? Vs1 : Vs0;
    u16* Vn = (kt & 1) ? Vs0 : Vs1;
    const bool more1 = (kt + 1 < NT);
    const bool more2 = (kt + 2 < NT);

    // issue tile kt+2 loads (landing deadline: write at iteration kt+1)
    uint4 kB0 = {}, kB1 = {}, vB0 = {}, vB1 = {};
    if (more2) {
      const u16* s = Kg + (size_t)(k0 + 128 + skey) * AHD + sj * 8;
      kB0 = ((const uint4*)s)[0]; kB1 = ((const uint4*)s)[1];
      if (DO_PV) {
        const u16* sv = Vg + (size_t)skey * SLK + (k0 + 128) + sj * 8;
        vB0 = ((const uint4*)sv)[0]; vB1 = ((const uint4*)sv)[1];
      }
    }

    // QK^T (swapped): 16 MFMA
    f32x4 sacc[2][4];
#pragma unroll
    for (int mt = 0; mt < 2; ++mt)
#pragma unroll
      for (int ct = 0; ct < 4; ++ct) sacc[mt][ct] = (f32x4){0.f, 0.f, 0.f, 0.f};
    __builtin_amdgcn_s_setprio(1);
#pragma unroll
    for (int ct = 0; ct < 4; ++ct) {
      const int krow = ct * 16 + lr;
      f16x8 kf0 = ldsF8(&Kc[krow * 64 + ((lg)     ^ (krow & 7)) * 8]);
      f16x8 kf1 = ldsF8(&Kc[krow * 64 + ((4 + lg) ^ (krow & 7)) * 8]);
      sacc[0][ct] = __builtin_amdgcn_mfma_f32_16x16x32_f16(kf0, qa[0][0], sacc[0][ct], 0, 0, 0);
      sacc[0][ct] = __builtin_amdgcn_mfma_f32_16x16x32_f16(kf1, qa[0][1], sacc[0][ct], 0, 0, 0);
      sacc[1][ct] = __builtin_amdgcn_mfma_f32_16x16x32_f16(kf0, qa[1][0], sacc[1][ct], 0, 0, 0);
      sacc[1][ct] = __builtin_amdgcn_mfma_f32_16x16x32_f16(kf1, qa[1][1], sacc[1][ct], 0, 0, 0);
    }
    __builtin_amdgcn_s_setprio(0);

    // softmax numerators (p overwrites sacc); mask multiplicative from LDS
    float ps[2] = {0.f, 0.f};
#pragma unroll
    for (int ct = 0; ct < 4; ++ct) {
      const float4 mm = *(const float4*)&Msf[k0 + ct * 16 + lg * 4];
      const float m4[4] = {mm.x, mm.y, mm.z, mm.w};
#pragma unroll
      for (int mt = 0; mt < 2; ++mt)
#pragma unroll
        for (int r = 0; r < 4; ++r) {
          float p = __expf(sacc[mt][ct][r] * scale) * m4[r];
          if (NORM_P) p *= invl[mt];
          sacc[mt][ct][r] = p;
          if (ACC_L) ps[mt] += p;
        }
    }
    if (ACC_L) {
#pragma unroll
      for (int mt = 0; mt < 2; ++mt) {
        float s = ps[mt];
        s += __shfl_xor(s, 16);
        s += __shfl_xor(s, 32);
        lrun[mt] += s;
      }
    }

    if (NORM_P) {
      // p2 write: contiguous float4 along k per (mt,ct)
#pragma unroll
      for (int mt = 0; mt < 2; ++mt)
#pragma unroll
        for (int ct = 0; ct < 4; ++ct) {
          float4 pv = make_float4(sacc[mt][ct][0], sacc[mt][ct][1], sacc[mt][ct][2], sacc[mt][ct][3]);
          *(float4*)&Pout[(poutRow0 + mt * 16 + lr) * (size_t)SLK + k0 + ct * 16 + lg * 4] = pv;
        }
    }

    if (DO_PV) {
      // In-register P -> A-frag redistribution (T12)
      f16x8 pa[2][2];
#pragma unroll
      for (int mt = 0; mt < 2; ++mt) {
#pragma unroll
        for (int ks = 0; ks < 2; ++ks) {
          unsigned s00 = pk2(sacc[mt][2 * ks][0],     sacc[mt][2 * ks][1]);
          unsigned s01 = pk2(sacc[mt][2 * ks][2],     sacc[mt][2 * ks][3]);
          unsigned s10 = pk2(sacc[mt][2 * ks + 1][0], sacc[mt][2 * ks + 1][1]);
          unsigned s11 = pk2(sacc[mt][2 * ks + 1][2], sacc[mt][2 * ks + 1][3]);
          asm volatile("v_permlane32_swap_b32 %0, %1" : "+v"(s00), "+v"(s10));
          asm volatile("v_permlane16_swap_b32 %0, %1" : "+v"(s00), "+v"(s10));
          asm volatile("v_permlane32_swap_b32 %0, %1" : "+v"(s01), "+v"(s11));
          asm volatile("v_permlane16_swap_b32 %0, %1" : "+v"(s01), "+v"(s11));
          F8 u;
          u.u4 = make_uint4(s00, s01, s10, s11);
          pa[mt][ks] = u.v;
        }
      }

      // V fragments from LDS (compiler inserts the lgkmcnt before MFMA use)
      f16x8 vf[4][2];
#pragma unroll
      for (int dt = 0; dt < 4; ++dt) {
        const int vrow = dt * 16 + lr;
        vf[dt][0] = ldsF8(&Vc[vrow * 64 + ((lg)     ^ (vrow & 7)) * 8]);
        vf[dt][1] = ldsF8(&Vc[vrow * 64 + ((4 + lg) ^ (vrow & 7)) * 8]);
      }

      __builtin_amdgcn_s_setprio(1);
#pragma unroll
      for (int dt = 0; dt < 4; ++dt) {
        oacc[0][dt] = __builtin_amdgcn_mfma_f32_16x16x32_f16(pa[0][0], vf[dt][0], oacc[0][dt], 0, 0, 0);
        oacc[0][dt] = __builtin_amdgcn_mfma_f32_16x16x32_f16(pa[0][1], vf[dt][1], oacc[0][dt], 0, 0, 0);
        oacc[1][dt] = __builtin_amdgcn_mfma_f32_16x16x32_f16(pa[1][0], vf[dt][0], oacc[1][dt], 0, 0, 0);
        oacc[1][dt] = __builtin_amdgcn_mfma_f32_16x16x32_f16(pa[1][1], vf[dt][1], oacc[1][dt], 0, 0, 0);
      }
      __builtin_amdgcn_s_setprio(0);
    }

    // write tile kt+1 (loaded last iteration) into the next LDS buffer
    if (more1) {
      *(uint4*)&Kn[skey * 64 + ((sj)     ^ (skey & 7)) * 8] = kA0;
      *(uint4*)&Kn[skey * 64 + ((sj + 1) ^ (skey & 7)) * 8] = kA1;
      if (DO_PV) {
        *(uint4*)&Vn[skey * 64 + ((sj)     ^ (skey & 7)) * 8] = vA0;
        *(uint4*)&Vn[skey * 64 + ((sj + 1) ^ (skey & 7)) * 8] = vA1;
      }
    }
    kA0 = kB0; kA1 = kB1; vA0 = vB0; vA1 = vB1;
    __syncthreads();
  }
}

// MODE 0: stage 1 — single pass, unnormalized PV + denom, writes O fp16 + O^T fp16.
// MODE 1: stage 2 — pass1 (denoms), pass2 (normalized p2 f32 + PV), writes tanh f32.
template <int MODE>
__global__ __launch_bounds__(256) void attn_mfma(
    const u16* __restrict__ Qm, const u16* __restrict__ Km,
    const u16* __restrict__ Vt, const int* __restrict__ mask,
    u16* __restrict__ O16, u16* __restrict__ O16t,
    float* __restrict__ Of32, float* __restrict__ Pout) {
  __shared__ __align__(16) u16 Ks[2][64 * 64];
  __shared__ __align__(16) u16 Vs[2][64 * 64];
  __shared__ __align__(16) float Msf[SLK];

  const int t  = threadIdx.x;
  const int w  = t >> 6, l = t & 63;
  const int lr = l & 15, lg = l >> 4;
  const int b  = blockIdx.y, h = blockIdx.z;
  const int qr0 = blockIdx.x * 128 + w * 32;

  // mask -> LDS as float 0/1 (visible after attn_pass's prologue barrier)
  {
    const int4 mi = ((const int4*)(mask + (size_t)b * SLK))[t];
    *(float4*)&Msf[t * 4] = make_float4(mi.x == 1 ? 1.f : 0.f, mi.y == 1 ? 1.f : 0.f,
                                        mi.z == 1 ? 1.f : 0.f, mi.w == 1 ? 1.f : 0.f);
  }

  // Q fragments (held across passes)
  f16x8 qa[2][2];
#pragma unroll
  for (int mt = 0; mt < 2; ++mt) {
    const u16* qp = Qm + (size_t)(b * SLQ + qr0 + mt * 16 + lr) * AHD + h * DH + lg * 8;
    qa[mt][0] = *(const f16x8*)qp;
    qa[mt][1] = *(const f16x8*)(qp + 32);
  }

  const u16* Kg = Km + (size_t)b * SLK * AHD + h * DH;
  const u16* Vg = Vt + ((size_t)b * AHD + h * DH) * SLK;
  const size_t poutRow0 = ((size_t)(h * BB + b)) * SLQ + qr0;
  const int skey = t >> 2, sj = (t & 3) * 2;

  float lrun[2] = {0.f, 0.f};
  float invl[2] = {1.f, 1.f};
  f32x4 oacc[2][4];
#pragma unroll
  for (int mt = 0; mt < 2; ++mt)
#pragma unroll
    for (int dt = 0; dt < 4; ++dt) oacc[mt][dt] = (f32x4){0.f, 0.f, 0.f, 0.f};

  if (MODE == 0) {
    attn_pass<true, false, true>(Kg, Vg, Msf, Ks[0], Ks[1], Vs[0], Vs[1],
                                 qa, lr, lg, lrun, invl, oacc, nullptr, 0, skey, sj);
#pragma unroll
    for (int mt = 0; mt < 2; ++mt) invl[mt] = 1.f / lrun[mt];
#pragma unroll
    for (int mt = 0; mt < 2; ++mt) {
      float iv[4];
#pragma unroll
      for (int r = 0; r < 4; ++r) iv[r] = __shfl(invl[mt], lg * 4 + r);
#pragma unroll
      for (int dt = 0; dt < 4; ++dt) {
        const int d = h * DH + dt * 16 + lr;
#pragma unroll
        for (int r = 0; r < 4; ++r) {
          const int q = qr0 + mt * 16 + lg * 4 + r;
          const u16 hv = f2h(oacc[mt][dt][r] * iv[r]);
          O16[(size_t)(b * SLQ + q) * AHD + d] = hv;
          O16t[((size_t)b * AHD + d) * SLQ + q] = hv;
        }
      }
    }
  } else {
    attn_pass<false, false, true>(Kg, Vg, Msf, Ks[0], Ks[1], Vs[0], Vs[1],
                                  qa, lr, lg, lrun, invl, oacc, nullptr, 0, skey, sj);
#pragma unroll
    for (int mt = 0; mt < 2; ++mt) invl[mt] = 1.f / lrun[mt];
    attn_pass<true, true, false>(Kg, Vg, Msf, Ks[0], Ks[1], Vs[0], Vs[1],
                                 qa, lr, lg, lrun, invl, oacc, Pout, poutRow0, skey, sj);
#pragma unroll
    for (int mt = 0; mt < 2; ++mt)
#pragma unroll
      for (int dt = 0; dt < 4; ++dt) {
        const int d = h * DH + dt * 16 + lr;
#pragma unroll
        for (int r = 0; r < 4; ++r) {
          const int q = qr0 + mt * 16 + lg * 4 + r;
          Of32[(size_t)(b * SLQ + q) * AHD + d] = fast_tanh(oacc[mt][dt][r]);
        }
      }
  }
}

extern "C" void kernel_launch(void* const* d_in, const int* in_sizes, int n_in,
                              void* d_out, int out_size, void* d_ws, size_t ws_size,
                              hipStream_t stream) {
  const float* query = (const float*)d_in[0];
  const float* key   = (const float*)d_in[1];
  const int*   qmask = (const int*)d_in[2];
  const int*   kmask = (const int*)d_in[3];
  const float* Wq = (const float*)d_in[4];
  const float* bq = (const float*)d_in[5];
  const float* Wk = (const float*)d_in[6];
  const float* bk = (const float*)d_in[7];
  const float* Wv = (const float*)d_in[8];
  const float* bv = (const float*)d_in[9];

  float* out = (float*)d_out;
  const size_t bufE = (size_t)BB * SLQ * AHD;  // 6,291,456
  const size_t wE   = (size_t)AHD * DIM;       // 589,824
  float* p2out = out + bufE;                   // [H,B,LQ,LK] region (402 MB)

  // fp16 scratch in the not-yet-written p2 region (all dead before stage-2 writes p2):
  u16* Qb   = (u16*)p2out;
  u16* Kb   = Qb + bufE;
  u16* Vtb  = Kb + bufE;       // V^T [B,768,1024]
  u16* q16  = Vtb + bufE;
  u16* k16  = q16 + bufE;
  u16* wq16 = k16 + bufE;
  u16* wk16 = wq16 + wE;
  u16* wv16 = wk16 + wE;
  // O1 / O1^T in d_ws (read by stage 2 while p2 is written):
  u16* O1  = (u16*)d_ws;
  u16* O1t = O1 + bufE;

  cvt_f16<<<dim3(512, 5), dim3(256), 0, stream>>>(query, key, Wq, Wk, Wv,
                                                  q16, k16, wq16, wk16, wv16);

  dim3 pgrid(8192 / 128, DIM / 128, 3);  // (64, 6, 3) = 1152 blocks
  proj_mfma<<<pgrid, dim3(256), 0, stream>>>(q16, k16, wq16, wk16, wv16,
                                             bq, bk, bv, Qb, Kb, Vtb);

  dim3 agrid(SLQ / 128, BB, NH);  // (8, 8, 12) = 768 blocks, 3/CU
  attn_mfma<0><<<agrid, dim3(256), 0, stream>>>(Qb, Kb, Vtb, kmask, O1, O1t, nullptr, nullptr);
  attn_mfma<1><<<agrid, dim3(256), 0, stream>>>(O1, O1, O1t, qmask, nullptr, nullptr, out, p2out);
}